// Round 4
// baseline (90.703 us; speedup 1.0000x reference)
//
#include <hip/hip_runtime.h>
#include <stdint.h>

// y[n,i] = relu(b[idx[n],i] + sum_o w[idx[n],i,o] * x[n,o])
// B=8192, 64 models, 256x256 fp32.
//
// R4: two-kernel split, B restructured for 2-blocks/CU co-residency.
//  A) compact_kernel (unchanged): 64 blocks scan idx, write compacted sample
//     ids (rid_g[64][256], -1 padded) + counts.
//  B) gemm_kernel: 512 blocks (64 models x 4 sample-tiles of 64 x 2 col-tiles)
//     x 512 threads (8 waves, 2m x 4n grid of 32x32 tiles). LDS: x full-K
//     (33.8 KB) + w in TWO k-half phases reusing one 33.8 KB buffer ->
//     ~68 KB/block -> 2 blocks resident per CU. One block's MFMA/barrier
//     phases overlap the other's staging stalls (the counters show all pipes
//     idle: stall absorption, not bandwidth, is the limiter). Empty tiles
//     exit instantly leaving a live co-resident partner. XCD-bijective
//     swizzle (proven L2 retention in R2) keeps a model's 8 blocks on 1 XCD.

#define N_MODELS 64
#define IN_F     256
#define OUT_F    256
#define BATCH    8192
#define BM       64    // sample rows per tile
#define BN       128   // out cols per block
#define PKX      264   // x LDS pitch (bf16), full K: 256+8
#define PKW      132   // w LDS pitch (bf16), half K: 128+4

typedef __bf16 bf16x8 __attribute__((ext_vector_type(8)));
typedef float  f32x4  __attribute__((ext_vector_type(4)));

__device__ __forceinline__ bf16x8 pack8(float4 a, float4 b) {
  bf16x8 o;                       // native casts -> v_cvt_pk_bf16_f32
  o[0] = (__bf16)a.x; o[1] = (__bf16)a.y; o[2] = (__bf16)a.z; o[3] = (__bf16)a.w;
  o[4] = (__bf16)b.x; o[5] = (__bf16)b.y; o[6] = (__bf16)b.z; o[7] = (__bf16)b.w;
  return o;
}

// ---- kernel A: per-model compaction into workspace ----
__global__ __launch_bounds__(1024) void compact_kernel(
    const int* __restrict__ idxs, int* __restrict__ rid_g,
    int* __restrict__ cnt_g) {
  const int model = blockIdx.x;
  const int t     = threadIdx.x;
  const int lane  = t & 63;
  const int wv    = t >> 6;          // 0..15
  __shared__ int wsum[16];

  const int4* ip = (const int4*)idxs + t * 2;   // 8 idxs/thread
  int4 iv0 = ip[0], iv1 = ip[1];

  int cnt = (iv0.x == model) + (iv0.y == model) + (iv0.z == model) + (iv0.w == model)
          + (iv1.x == model) + (iv1.y == model) + (iv1.z == model) + (iv1.w == model);
  int inc = cnt;
#pragma unroll
  for (int d = 1; d < 64; d <<= 1) {
    int u = __shfl_up(inc, d);
    if (lane >= d) inc += u;
  }
  if (lane == 63) wsum[wv] = inc;
  __syncthreads();
  int wpre = 0, total = 0;
#pragma unroll
  for (int j = 0; j < 16; ++j) {
    int s = wsum[j];
    total += s;
    if (j < wv) wpre += s;
  }
  int off = wpre + inc - cnt;
  int* rg = rid_g + model * 256;
  {
    int n0 = t * 8;
    if (iv0.x == model) { if ((unsigned)off < 256u) rg[off] = n0 + 0; ++off; }
    if (iv0.y == model) { if ((unsigned)off < 256u) rg[off] = n0 + 1; ++off; }
    if (iv0.z == model) { if ((unsigned)off < 256u) rg[off] = n0 + 2; ++off; }
    if (iv0.w == model) { if ((unsigned)off < 256u) rg[off] = n0 + 3; ++off; }
    if (iv1.x == model) { if ((unsigned)off < 256u) rg[off] = n0 + 4; ++off; }
    if (iv1.y == model) { if ((unsigned)off < 256u) rg[off] = n0 + 5; ++off; }
    if (iv1.z == model) { if ((unsigned)off < 256u) rg[off] = n0 + 6; ++off; }
    if (iv1.w == model) { if ((unsigned)off < 256u) rg[off] = n0 + 7; ++off; }
  }
  if (t < 256 && t >= total) rg[t] = -1;   // pad tail
  if (t == 0) cnt_g[model] = total;
}

// ---- kernel B: gathered GEMM, 2 blocks/CU ----
__global__ __launch_bounds__(512) void gemm_kernel(
    const float* __restrict__ x, const float* __restrict__ w,
    const float* __restrict__ bias_g, float* __restrict__ out,
    const int* __restrict__ rid_g, const int* __restrict__ cnt_g) {
  // XCD-bijective swizzle (512 % 8 == 0): a model's 8 blocks -> one XCD
  const int b     = (blockIdx.x & 7) * 64 + (blockIdx.x >> 3);
  const int model = b >> 3;
  const int s     = (b >> 1) & 3;    // sample-tile (rows s*64 ..)
  const int i0    = (b & 1) * BN;    // out-col tile
  const int t     = threadIdx.x;
  const int lane  = t & 63;
  const int wv    = t >> 6;          // 0..7

  __shared__ unsigned short a_lds[BM][PKX];  // gathered x rows, bf16, full K
  __shared__ unsigned short b_lds[BN][PKW];  // w rows, bf16, one k-half
  __shared__ int rid[BM];

  const int total = cnt_g[model];
  if (s * BM >= total) return;       // block-uniform early exit

  // rid loads first (critical path for x gather)
  if (t < BM) rid[t] = rid_g[model * 256 + s * BM + t];
  const int rwx  = t >> 3;           // x staged row (8 thr/row), 0..63
  const int hx   = t & 7;            // 32-float chunk (full K)
  const int srow = rid_g[model * 256 + s * BM + rwx];

  // ---- w staging phase 0: k in [0,128) (independent; issues under rid) ----
  const int rww = t >> 2;            // w staged row (4 thr/row), 0..127
  const int hw  = t & 3;             // 32-float chunk of the k-half
  const float* wrow = w + (size_t)model * (IN_F * OUT_F)
                        + (size_t)(i0 + rww) * IN_F + hw * 32;
  {
    float4 tw[8];
#pragma unroll
    for (int j = 0; j < 8; ++j) tw[j] = *(const float4*)(wrow + j * 4);
#pragma unroll
    for (int j = 0; j < 4; ++j)
      *(bf16x8*)&b_lds[rww][hw * 32 + j * 8] = pack8(tw[2 * j], tw[2 * j + 1]);
  }

  // ---- x staging, full K (invalid rows read row 0, never stored) ----
  const float* xrow = x + (size_t)(srow < 0 ? 0 : srow) * IN_F + hx * 32;
  {
    float4 tx[8];
#pragma unroll
    for (int j = 0; j < 8; ++j) tx[j] = *(const float4*)(xrow + j * 4);
#pragma unroll
    for (int j = 0; j < 4; ++j)
      *(bf16x8*)&a_lds[rwx][hx * 32 + j * 8] = pack8(tx[2 * j], tx[2 * j + 1]);
  }

  // wave tile coords + bias (issued while staging drains)
  const int wm   = (wv & 1) * 32;    // 2 m-tiles of 32 rows
  const int wn   = (wv >> 1) * 32;   // 4 n-tiles of 32 cols
  const int col  = lane & 15;
  const int quad = lane >> 4;
  float bv[2];
  const float* bp = bias_g + model * OUT_F + i0 + wn + col;
#pragma unroll
  for (int nt = 0; nt < 2; ++nt) bv[nt] = bp[nt * 16];

  __syncthreads();                   // B1: x full, w half0, rid ready

  f32x4 acc[2][2];                   // bias folded into acc init
#pragma unroll
  for (int mt = 0; mt < 2; ++mt)
#pragma unroll
    for (int nt = 0; nt < 2; ++nt)
      acc[mt][nt] = (f32x4){bv[nt], bv[nt], bv[nt], bv[nt]};

  // ---- k-half 0: 4 k-steps x 4 MFMA per wave ----
#pragma unroll
  for (int ks = 0; ks < 4; ++ks) {
    bf16x8 af[2], bfr[2];
#pragma unroll
    for (int mt = 0; mt < 2; ++mt)
      af[mt] = *(const bf16x8*)&a_lds[wm + mt * 16 + col][ks * 32 + quad * 8];
#pragma unroll
    for (int nt = 0; nt < 2; ++nt)
      bfr[nt] = *(const bf16x8*)&b_lds[wn + nt * 16 + col][ks * 32 + quad * 8];
#pragma unroll
    for (int mt = 0; mt < 2; ++mt)
#pragma unroll
      for (int nt = 0; nt < 2; ++nt)
        acc[mt][nt] = __builtin_amdgcn_mfma_f32_16x16x32_bf16(
            af[mt], bfr[nt], acc[mt][nt], 0, 0, 0);
  }

  __syncthreads();                   // B2: done reading w half0

  // ---- w staging phase 1: k in [128,256), same buffer ----
  {
    float4 tw[8];
#pragma unroll
    for (int j = 0; j < 8; ++j) tw[j] = *(const float4*)(wrow + 128 + j * 4);
#pragma unroll
    for (int j = 0; j < 4; ++j)
      *(bf16x8*)&b_lds[rww][hw * 32 + j * 8] = pack8(tw[2 * j], tw[2 * j + 1]);
  }

  __syncthreads();                   // B3: w half1 ready

  // ---- k-half 1: accumulate into the SAME acc ----
#pragma unroll
  for (int ks = 4; ks < 8; ++ks) {
    bf16x8 af[2], bfr[2];
#pragma unroll
    for (int mt = 0; mt < 2; ++mt)
      af[mt] = *(const bf16x8*)&a_lds[wm + mt * 16 + col][ks * 32 + quad * 8];
#pragma unroll
    for (int nt = 0; nt < 2; ++nt)
      bfr[nt] = *(const bf16x8*)&b_lds[wn + nt * 16 + col][(ks - 4) * 32 + quad * 8];
#pragma unroll
    for (int mt = 0; mt < 2; ++mt)
#pragma unroll
      for (int nt = 0; nt < 2; ++nt)
        acc[mt][nt] = __builtin_amdgcn_mfma_f32_16x16x32_bf16(
            af[mt], bfr[nt], acc[mt][nt], 0, 0, 0);
  }

  // ---- epilogue: relu + scatter by sample id ----
#pragma unroll
  for (int mt = 0; mt < 2; ++mt) {
#pragma unroll
    for (int reg = 0; reg < 4; ++reg) {
      const int mm = wm + mt * 16 + quad * 4 + reg;   // C/D: row = quad*4+reg
      const int sle = rid[mm];
      if (sle >= 0) {
        float* orow = out + (size_t)sle * OUT_F + i0 + wn + col;
#pragma unroll
        for (int nt = 0; nt < 2; ++nt)
          orow[nt * 16] = fmaxf(acc[mt][nt][reg], 0.0f);
      }
    }
  }
}

extern "C" void kernel_launch(void* const* d_in, const int* in_sizes, int n_in,
                              void* d_out, int out_size, void* d_ws, size_t ws_size,
                              hipStream_t stream) {
  const float* x    = (const float*)d_in[0];
  const int*   idxs = (const int*)d_in[1];
  const float* w    = (const float*)d_in[2];
  const float* b    = (const float*)d_in[3];
  float* out = (float*)d_out;

  int* rid_g = (int*)d_ws;              // 64*256 ints
  int* cnt_g = rid_g + N_MODELS * 256;  // 64 ints

  compact_kernel<<<N_MODELS, 1024, 0, stream>>>(idxs, rid_g, cnt_g);
  gemm_kernel<<<N_MODELS * 8, 512, 0, stream>>>(x, w, b, out, rid_g, cnt_g);
}

// Round 5
// 86.390 us; speedup vs baseline: 1.0499x; 1.0499x over previous
//
#include <hip/hip_runtime.h>
#include <stdint.h>

// y[n,i] = relu(b[idx[n],i] + sum_o w[idx[n],i,o] * x[n,o])
// B=8192, 64 models, 256x256 fp32.
//
// R5: A (per-model compaction, unchanged) + B rebuilt around global_load_lds.
//  B: 256 blocks (64 models x 2 sample-tiles x 2 out-tiles), 1024 thr,
//     16 waves in a 4x4 grid of 32x32 tiles. w staged as RAW F32 via
//     global_load_lds DMA (no VGPR roundtrip -> whole tile in flight: fixes
//     the measured MLP limit, ingest was 1.9 TB/s because reg-staging keeps
//     only ~4 KB/CU outstanding). Quarter-K double buffer (2 x 128x64 f32),
//     XOR-16B-chunk swizzle folded into the per-lane GLOBAL address (LDS dest
//     stays linear as the DMA requires; reads apply the same XOR) -> b128
//     reads at the 8-cycle floor. Pipeline with plain __syncthreads only:
//     issue q0+q1; [B; mfma q0; B; issue q2; mfma q1; B; issue q3; mfma q2;
//     B; mfma q3] - each barrier's vmcnt drain is exactly the DMA needed
//     next, so no raw-barrier races. x stays bf16 reg-staged (gathered).

#define N_MODELS 64
#define IN_F     256
#define OUT_F    256
#define BATCH    8192
#define BM       128
#define BN       128
#define PKX      264   // x LDS pitch bf16: 256+8

typedef __bf16 bf16x8 __attribute__((ext_vector_type(8)));
typedef float  f32x4  __attribute__((ext_vector_type(4)));
typedef __attribute__((address_space(3))) uint32_t lds_u32;
typedef const __attribute__((address_space(1))) uint32_t glb_u32;

__device__ __forceinline__ void dma16(const void* g, void* l) {
  __builtin_amdgcn_global_load_lds((glb_u32*)g, (lds_u32*)l, 16, 0, 0);
}

__device__ __forceinline__ bf16x8 pack8(float4 a, float4 b) {
  bf16x8 o;                       // native casts -> v_cvt_pk_bf16_f32
  o[0] = (__bf16)a.x; o[1] = (__bf16)a.y; o[2] = (__bf16)a.z; o[3] = (__bf16)a.w;
  o[4] = (__bf16)b.x; o[5] = (__bf16)b.y; o[6] = (__bf16)b.z; o[7] = (__bf16)b.w;
  return o;
}

// ---- kernel A: per-model compaction into workspace (unchanged) ----
__global__ __launch_bounds__(1024) void compact_kernel(
    const int* __restrict__ idxs, int* __restrict__ rid_g,
    int* __restrict__ cnt_g) {
  const int model = blockIdx.x;
  const int t     = threadIdx.x;
  const int lane  = t & 63;
  const int wv    = t >> 6;          // 0..15
  __shared__ int wsum[16];

  const int4* ip = (const int4*)idxs + t * 2;   // 8 idxs/thread
  int4 iv0 = ip[0], iv1 = ip[1];

  int cnt = (iv0.x == model) + (iv0.y == model) + (iv0.z == model) + (iv0.w == model)
          + (iv1.x == model) + (iv1.y == model) + (iv1.z == model) + (iv1.w == model);
  int inc = cnt;
#pragma unroll
  for (int d = 1; d < 64; d <<= 1) {
    int u = __shfl_up(inc, d);
    if (lane >= d) inc += u;
  }
  if (lane == 63) wsum[wv] = inc;
  __syncthreads();
  int wpre = 0, total = 0;
#pragma unroll
  for (int j = 0; j < 16; ++j) {
    int s = wsum[j];
    total += s;
    if (j < wv) wpre += s;
  }
  int off = wpre + inc - cnt;
  int* rg = rid_g + model * 256;
  {
    int n0 = t * 8;
    if (iv0.x == model) { if ((unsigned)off < 256u) rg[off] = n0 + 0; ++off; }
    if (iv0.y == model) { if ((unsigned)off < 256u) rg[off] = n0 + 1; ++off; }
    if (iv0.z == model) { if ((unsigned)off < 256u) rg[off] = n0 + 2; ++off; }
    if (iv0.w == model) { if ((unsigned)off < 256u) rg[off] = n0 + 3; ++off; }
    if (iv1.x == model) { if ((unsigned)off < 256u) rg[off] = n0 + 4; ++off; }
    if (iv1.y == model) { if ((unsigned)off < 256u) rg[off] = n0 + 5; ++off; }
    if (iv1.z == model) { if ((unsigned)off < 256u) rg[off] = n0 + 6; ++off; }
    if (iv1.w == model) { if ((unsigned)off < 256u) rg[off] = n0 + 7; ++off; }
  }
  if (t < 256 && t >= total) rg[t] = -1;   // pad tail
  if (t == 0) cnt_g[model] = total;
}

// ---- kernel B: gathered GEMM with DMA'd w ----
__global__ __launch_bounds__(1024) void gemm_kernel(
    const float* __restrict__ x, const float* __restrict__ w,
    const float* __restrict__ bias_g, float* __restrict__ out,
    const int* __restrict__ rid_g, const int* __restrict__ cnt_g) {
  // XCD-bijective swizzle (256 % 8 == 0): a model's 4 blocks -> one XCD
  const int b     = (blockIdx.x & 7) * 32 + (blockIdx.x >> 3);
  const int model = b >> 2;
  const int s     = (b >> 1) & 1;    // sample-tile (rows s*128 ..)
  const int i0    = (b & 1) * BN;    // out-col tile
  const int t     = threadIdx.x;
  const int lane  = t & 63;
  const int wv    = t >> 6;          // 0..15

  __shared__ float w_lds[2][BM][64];        // quarter-K f32, dbuf, DMA dest
  __shared__ unsigned short a_lds[BM][PKX]; // gathered x rows, bf16, full K
  __shared__ int rid[BM];

  const int total = cnt_g[model];
  if (s * BM >= total) return;       // block-uniform early exit (pre-barrier)

  // rid loads first (critical path for x gather)
  if (t < BM) rid[t] = rid_g[model * 256 + s * BM + t];
  const int rwx  = t >> 3;           // x staged row (8 thr/row), 0..127
  const int hx   = t & 7;            // 32-float chunk (full K)
  const int srow = rid_g[model * 256 + s * BM + rwx];

  // ---- w DMA: quarter q, half j -> one 1024B wave-instruction covers
  //      4 rows x 16 chunks of 16B. Per-lane GLOBAL addr carries the XOR
  //      swizzle; LDS dest is linear (base + lane*16, HW requirement).
  const float* wbase = w + (size_t)model * (IN_F * OUT_F) + (size_t)i0 * IN_F;
  const int l_r = lane >> 4;         // row within the 4-row group
  const int l_c = lane & 15;         // 16B chunk within the row
#define W_DMA(q, buf)                                                        \
  {                                                                          \
    _Pragma("unroll")                                                        \
    for (int j = 0; j < 2; ++j) {                                            \
      const int r0 = wv * 8 + j * 4;                                         \
      const int rr = r0 + l_r;                                               \
      const float* gs = wbase + (size_t)rr * IN_F + (q) * 64                 \
                        + ((l_c ^ (rr & 7)) << 2);                           \
      dma16(gs, &w_lds[buf][r0][0]);                                         \
    }                                                                        \
  }

  // issue q0+q1 immediately: ~64 KB/CU in flight (the MLP fix)
  W_DMA(0, 0)
  W_DMA(1, 1)

  // ---- x staging, full K, bf16 (invalid rows read row 0, never stored) ----
  const float* xrow = x + (size_t)(srow < 0 ? 0 : srow) * IN_F + hx * 32;
  {
    float4 tx[8];
#pragma unroll
    for (int j = 0; j < 8; ++j) tx[j] = *(const float4*)(xrow + j * 4);
#pragma unroll
    for (int j = 0; j < 4; ++j)
      *(bf16x8*)&a_lds[rwx][hx * 32 + j * 8] = pack8(tx[2 * j], tx[2 * j + 1]);
  }

  // wave tile coords + bias (issued while staging drains)
  const int wm   = (wv & 3) * 32;    // 4x4 wave grid of 32x32 tiles
  const int wn   = (wv >> 2) * 32;
  const int col  = lane & 15;
  const int quad = lane >> 4;
  float bv[2];
  const float* bp = bias_g + model * OUT_F + i0 + wn + col;
#pragma unroll
  for (int nt = 0; nt < 2; ++nt) bv[nt] = bp[nt * 16];

  __syncthreads();                   // B1: drains q0,q1 DMA + x/rid writes

  f32x4 acc[2][2];                   // bias folded into acc init
#pragma unroll
  for (int mt = 0; mt < 2; ++mt)
#pragma unroll
    for (int nt = 0; nt < 2; ++nt)
      acc[mt][nt] = (f32x4){bv[nt], bv[nt], bv[nt], bv[nt]};

  // one quarter = 2 k-steps; w frag read applies the same XOR swizzle
#define MFMA_QUARTER(buf, ks0)                                               \
  {                                                                          \
    _Pragma("unroll")                                                        \
    for (int kk = 0; kk < 2; ++kk) {                                         \
      const int ks  = (ks0) + kk;                                            \
      const int ch0 = kk * 8 + quad * 2;                                     \
      bf16x8 af[2], bfr[2];                                                  \
      _Pragma("unroll")                                                      \
      for (int mt = 0; mt < 2; ++mt)                                         \
        af[mt] = *(const bf16x8*)&a_lds[wm + mt * 16 + col]                  \
                                      [ks * 32 + quad * 8];                  \
      _Pragma("unroll")                                                      \
      for (int nt = 0; nt < 2; ++nt) {                                       \
        const int R  = wn + nt * 16 + col;                                   \
        const int sw = R & 7;                                                \
        float4 f0 = *(const float4*)&w_lds[buf][R][((ch0)     ^ sw) << 2];   \
        float4 f1 = *(const float4*)&w_lds[buf][R][((ch0 + 1) ^ sw) << 2];   \
        bfr[nt] = pack8(f0, f1);                                             \
      }                                                                      \
      _Pragma("unroll")                                                      \
      for (int mt = 0; mt < 2; ++mt)                                         \
        _Pragma("unroll")                                                    \
        for (int nt = 0; nt < 2; ++nt)                                       \
          acc[mt][nt] = __builtin_amdgcn_mfma_f32_16x16x32_bf16(             \
              af[mt], bfr[nt], acc[mt][nt], 0, 0, 0);                        \
    }                                                                        \
  }

  MFMA_QUARTER(0, 0)                 // q0
  __syncthreads();                   // B2: buf0 reads done
  W_DMA(2, 0)                        // refill buf0 (overlaps q1 mfma)
  MFMA_QUARTER(1, 2)                 // q1
  __syncthreads();                   // B3: drains q2 DMA; buf1 reads done
  W_DMA(3, 1)                        // refill buf1 (overlaps q2 mfma)
  MFMA_QUARTER(0, 4)                 // q2
  __syncthreads();                   // B4: drains q3 DMA
  MFMA_QUARTER(1, 6)                 // q3

  // ---- epilogue: relu + scatter by sample id ----
#pragma unroll
  for (int mt = 0; mt < 2; ++mt) {
#pragma unroll
    for (int reg = 0; reg < 4; ++reg) {
      const int mm = wm + mt * 16 + quad * 4 + reg;   // C/D: row = quad*4+reg
      const int sle = rid[mm];
      if (sle >= 0) {
        float* orow = out + (size_t)sle * OUT_F + i0 + wn + col;
#pragma unroll
        for (int nt = 0; nt < 2; ++nt)
          orow[nt * 16] = fmaxf(acc[mt][nt][reg], 0.0f);
      }
    }
  }
#undef W_DMA
#undef MFMA_QUARTER
}

extern "C" void kernel_launch(void* const* d_in, const int* in_sizes, int n_in,
                              void* d_out, int out_size, void* d_ws, size_t ws_size,
                              hipStream_t stream) {
  const float* x    = (const float*)d_in[0];
  const int*   idxs = (const int*)d_in[1];
  const float* w    = (const float*)d_in[2];
  const float* b    = (const float*)d_in[3];
  float* out = (float*)d_out;

  int* rid_g = (int*)d_ws;              // 64*256 ints
  int* cnt_g = rid_g + N_MODELS * 256;  // 64 ints

  compact_kernel<<<N_MODELS, 1024, 0, stream>>>(idxs, rid_g, cnt_g);
  gemm_kernel<<<N_MODELS * 4, 1024, 0, stream>>>(x, w, b, out, rid_g, cnt_g);
}

// Round 6
// 86.205 us; speedup vs baseline: 1.0522x; 1.0021x over previous
//
#include <hip/hip_runtime.h>
#include <stdint.h>

// y[n,i] = relu(b[idx[n],i] + sum_o w[idx[n],i,o] * x[n,o])
// B=8192, 64 models, 256x256 fp32.
//
// R6: single fused kernel = R0's in-block compaction + R5's global_load_lds
// w-pipeline, with the scan's block barriers converted to raw s_barrier +
// lgkmcnt(0)-only waits so the w DMA issued at t0 stays in flight across the
// compaction phase (a __syncthreads would vmcnt(0)-drain it). Removes the
// R3/R5 A-kernel + inter-kernel serialization entirely.
//  - 256 blocks (64 models x 2 sample-tiles x 2 out-tiles), 1024 thr,
//    16 waves in a 4x4 grid of 32x32 tiles; XCD-bijective swizzle.
//  - idx loads issued FIRST (in-order vmcnt: consuming idx then waits
//    vmcnt(16), not the DMAs), then w q0+q1 DMA (s==0 blocks; s==1 defer
//    until proven non-empty), then scan, x bf16 reg-staged gather.
//  - w: RAW f32 quarter-K double buffer (2 x 128x64), XOR-16B-chunk swizzle
//    folded into the per-lane GLOBAL address (LDS dest linear per HW rule;
//    reads apply the same XOR) -> conflict-free b128 reads.
//  - B1..B4 are plain __syncthreads: their vmcnt drain is exactly the
//    refill-DMA completion guarantee (R5-proven).

#define N_MODELS 64
#define IN_F     256
#define OUT_F    256
#define BATCH    8192
#define BM       128
#define BN       128
#define PKX      264   // x LDS pitch bf16: 256+8

typedef __bf16 bf16x8 __attribute__((ext_vector_type(8)));
typedef float  f32x4  __attribute__((ext_vector_type(4)));
typedef __attribute__((address_space(3))) uint32_t lds_u32;
typedef const __attribute__((address_space(1))) uint32_t glb_u32;

__device__ __forceinline__ void dma16(const void* g, void* l) {
  __builtin_amdgcn_global_load_lds((glb_u32*)g, (lds_u32*)l, 16, 0, 0);
}

// raw block barrier that waits LDS ops only -> w DMA (vmcnt) stays in flight
__device__ __forceinline__ void barrier_lds_only() {
  asm volatile("s_waitcnt lgkmcnt(0)" ::: "memory");
  __builtin_amdgcn_s_barrier();
  __builtin_amdgcn_sched_barrier(0);   // no hoisting of post-barrier LDS reads
}

__device__ __forceinline__ bf16x8 pack8(float4 a, float4 b) {
  bf16x8 o;                       // native casts -> v_cvt_pk_bf16_f32
  o[0] = (__bf16)a.x; o[1] = (__bf16)a.y; o[2] = (__bf16)a.z; o[3] = (__bf16)a.w;
  o[4] = (__bf16)b.x; o[5] = (__bf16)b.y; o[6] = (__bf16)b.z; o[7] = (__bf16)b.w;
  return o;
}

__global__ __launch_bounds__(1024) void fused_kernel(
    const float* __restrict__ x, const int* __restrict__ idxs,
    const float* __restrict__ w, const float* __restrict__ bias_g,
    float* __restrict__ out) {
  // XCD-bijective swizzle (256 % 8 == 0): a model's 4 blocks -> one XCD
  const int b     = (blockIdx.x & 7) * 32 + (blockIdx.x >> 3);
  const int model = b >> 2;
  const int s     = (b >> 1) & 1;    // sample-tile (rows s*128 ..)
  const int i0    = (b & 1) * BN;    // out-col tile
  const int t     = threadIdx.x;
  const int lane  = t & 63;
  const int wv    = t >> 6;          // 0..15

  __shared__ float w_lds[2][BM][64];        // quarter-K f32, dbuf, DMA dest
  __shared__ unsigned short a_lds[BM][PKX]; // gathered x rows, bf16, full K
  __shared__ int rid[BM];
  __shared__ int wsum[16];

  // ---- idx loads FIRST (scan critical path; in-order vmcnt) ----
  const int4* ip = (const int4*)idxs + t * 2;   // 8 idxs/thread
  int4 iv0 = ip[0], iv1 = ip[1];

  // ---- w DMA addressing ----
  const float* wbase = w + (size_t)model * (IN_F * OUT_F) + (size_t)i0 * IN_F;
  const int l_r = lane >> 4;         // row within the 4-row group
  const int l_c = lane & 15;         // 16B chunk within the row
#define W_DMA(q, buf)                                                        \
  {                                                                          \
    _Pragma("unroll")                                                        \
    for (int j = 0; j < 2; ++j) {                                            \
      const int r0 = wv * 8 + j * 4;                                         \
      const int rr = r0 + l_r;                                               \
      const float* gs = wbase + (size_t)rr * IN_F + (q) * 64                 \
                        + ((l_c ^ (rr & 7)) << 2);                           \
      dma16(gs, &w_lds[buf][r0][0]);                                         \
    }                                                                        \
  }

  // s==0 blocks never early-exit: issue q0+q1 now (64 KB/CU in flight,
  // survives the scan thanks to lgkm-only barriers)
  if (s == 0) { W_DMA(0, 0) W_DMA(1, 1) }

  if (t < BM) rid[t] = -1;

  // ---- compaction: thread t owns idxs[8t .. 8t+7] ----
  int cnt = (iv0.x == model) + (iv0.y == model) + (iv0.z == model) + (iv0.w == model)
          + (iv1.x == model) + (iv1.y == model) + (iv1.z == model) + (iv1.w == model);
  int inc = cnt;
#pragma unroll
  for (int d = 1; d < 64; d <<= 1) {
    int u = __shfl_up(inc, d);
    if (lane >= d) inc += u;
  }
  if (lane == 63) wsum[wv] = inc;
  barrier_lds_only();                // RAW-BAR-1: wsum + rid(-1) committed
  int wpre = 0, total = 0;
#pragma unroll
  for (int j = 0; j < 16; ++j) {
    int sj = wsum[j];
    total += sj;
    if (j < wv) wpre += sj;
  }
  const int start = s * BM;
  if (start >= total) return;        // block-uniform (only s==1 can exit;
                                     // those blocks issued no DMA yet)
  // s==1 proven non-empty: issue its w DMA now (overlaps rid + x phases)
  if (s == 1) { W_DMA(0, 0) W_DMA(1, 1) }

  int off = wpre + inc - cnt - start;
  {
    int n0 = t * 8;
    if (iv0.x == model) { if ((unsigned)off < BM) rid[off] = n0 + 0; ++off; }
    if (iv0.y == model) { if ((unsigned)off < BM) rid[off] = n0 + 1; ++off; }
    if (iv0.z == model) { if ((unsigned)off < BM) rid[off] = n0 + 2; ++off; }
    if (iv0.w == model) { if ((unsigned)off < BM) rid[off] = n0 + 3; ++off; }
    if (iv1.x == model) { if ((unsigned)off < BM) rid[off] = n0 + 4; ++off; }
    if (iv1.y == model) { if ((unsigned)off < BM) rid[off] = n0 + 5; ++off; }
    if (iv1.z == model) { if ((unsigned)off < BM) rid[off] = n0 + 6; ++off; }
    if (iv1.w == model) { if ((unsigned)off < BM) rid[off] = n0 + 7; ++off; }
  }
  barrier_lds_only();                // RAW-BAR-2: rid ready (DMA untouched)

  // ---- x staging (gathered rows; invalid rows read row 0, never stored) ----
  const int rwx = t >> 3;            // x staged row (8 thr/row), 0..127
  const int hx  = t & 7;             // 32-float chunk
  const int srow = rid[rwx];
  const float* xrow = x + (size_t)(srow < 0 ? 0 : srow) * IN_F + hx * 32;
  {
    float4 tx[8];
#pragma unroll
    for (int j = 0; j < 8; ++j) tx[j] = *(const float4*)(xrow + j * 4);
#pragma unroll
    for (int j = 0; j < 4; ++j)
      *(bf16x8*)&a_lds[rwx][hx * 32 + j * 8] = pack8(tx[2 * j], tx[2 * j + 1]);
  }

  // wave tile coords + bias (issued while staging drains)
  const int wm   = (wv & 3) * 32;    // 4x4 wave grid of 32x32 tiles
  const int wn   = (wv >> 2) * 32;
  const int col  = lane & 15;
  const int quad = lane >> 4;
  float bv[2];
  const float* bp = bias_g + model * OUT_F + i0 + wn + col;
#pragma unroll
  for (int nt = 0; nt < 2; ++nt) bv[nt] = bp[nt * 16];

  __syncthreads();                   // B1: full drain = q0,q1 + a_lds ready

  f32x4 acc[2][2];                   // bias folded into acc init
#pragma unroll
  for (int mt = 0; mt < 2; ++mt)
#pragma unroll
    for (int nt = 0; nt < 2; ++nt)
      acc[mt][nt] = (f32x4){bv[nt], bv[nt], bv[nt], bv[nt]};

  // one quarter = 2 k-steps; w frag read applies the same XOR swizzle
#define MFMA_QUARTER(buf, ks0)                                               \
  {                                                                          \
    _Pragma("unroll")                                                        \
    for (int kk = 0; kk < 2; ++kk) {                                         \
      const int ks  = (ks0) + kk;                                            \
      const int ch0 = kk * 8 + quad * 2;                                     \
      bf16x8 af[2], bfr[2];                                                  \
      _Pragma("unroll")                                                      \
      for (int mt = 0; mt < 2; ++mt)                                         \
        af[mt] = *(const bf16x8*)&a_lds[wm + mt * 16 + col]                  \
                                      [ks * 32 + quad * 8];                  \
      _Pragma("unroll")                                                      \
      for (int nt = 0; nt < 2; ++nt) {                                       \
        const int R  = wn + nt * 16 + col;                                   \
        const int sw = R & 7;                                                \
        float4 f0 = *(const float4*)&w_lds[buf][R][((ch0)     ^ sw) << 2];   \
        float4 f1 = *(const float4*)&w_lds[buf][R][((ch0 + 1) ^ sw) << 2];   \
        bfr[nt] = pack8(f0, f1);                                             \
      }                                                                      \
      _Pragma("unroll")                                                      \
      for (int mt = 0; mt < 2; ++mt)                                         \
        _Pragma("unroll")                                                    \
        for (int nt = 0; nt < 2; ++nt)                                       \
          acc[mt][nt] = __builtin_amdgcn_mfma_f32_16x16x32_bf16(             \
              af[mt], bfr[nt], acc[mt][nt], 0, 0, 0);                        \
    }                                                                        \
  }

  MFMA_QUARTER(0, 0)                 // q0
  __syncthreads();                   // B2: buf0 reads done
  W_DMA(2, 0)                        // refill buf0 (overlaps q1 mfma)
  MFMA_QUARTER(1, 2)                 // q1
  __syncthreads();                   // B3: drains q2 DMA; buf1 reads done
  W_DMA(3, 1)                        // refill buf1 (overlaps q2 mfma)
  MFMA_QUARTER(0, 4)                 // q2
  __syncthreads();                   // B4: drains q3 DMA
  MFMA_QUARTER(1, 6)                 // q3

  // ---- epilogue: relu + scatter by sample id ----
#pragma unroll
  for (int mt = 0; mt < 2; ++mt) {
#pragma unroll
    for (int reg = 0; reg < 4; ++reg) {
      const int mm = wm + mt * 16 + quad * 4 + reg;   // C/D: row = quad*4+reg
      const int sle = rid[mm];
      if (sle >= 0) {
        float* orow = out + (size_t)sle * OUT_F + i0 + wn + col;
#pragma unroll
        for (int nt = 0; nt < 2; ++nt)
          orow[nt * 16] = fmaxf(acc[mt][nt][reg], 0.0f);
      }
    }
  }
#undef W_DMA
#undef MFMA_QUARTER
}

extern "C" void kernel_launch(void* const* d_in, const int* in_sizes, int n_in,
                              void* d_out, int out_size, void* d_ws, size_t ws_size,
                              hipStream_t stream) {
  const float* x    = (const float*)d_in[0];
  const int*   idxs = (const int*)d_in[1];
  const float* w    = (const float*)d_in[2];
  const float* b    = (const float*)d_in[3];
  float* out = (float*)d_out;
  (void)d_ws; (void)ws_size;

  fused_kernel<<<N_MODELS * 4, 1024, 0, stream>>>(x, idxs, w, b, out);
}